// Round 3
// baseline (3528.899 us; speedup 1.0000x reference)
//
#include <hip/hip_runtime.h>
#include <hip/hip_cooperative_groups.h>
#include <math.h>

namespace cg = cooperative_groups;

// ---------------------------------------------------------------------------
// GP posterior mean: separable NUFFT outer products (fp32, atomic-free
// partials) -> fp64 reduce + 128x128 circulant Vf + 50-iter fp64 CG in ONE
// cooperative kernel (3 grid.sync per iter) -> eval at test points.
// ---------------------------------------------------------------------------

typedef float f2 __attribute__((ext_vector_type(2)));
#define PB 16

__device__ inline f2 f2s(float s) { return (f2){s, s}; }

__device__ inline void dmac(double2& acc, double2 a, double2 b) {
    acc.x = fma(a.x, b.x, fma(-a.y, b.y, acc.x));
    acc.y = fma(a.x, b.y, fma(a.y, b.x, acc.y));
}
__device__ inline void dmacc(double2& acc, double2 a, double2 b) {  // += a*conj(b)
    acc.x = fma(a.x, b.x, fma(a.y, b.y, acc.x));
    acc.y = fma(a.y, b.x, fma(-a.x, b.y, acc.y));
}

// exp(i*pi*x*m) with fp64 angle reduction, scaled
__device__ inline f2 phasef(float xv, float m, float scale) {
    double ang = (double)xv * (double)m;
    double r = ang - 2.0 * rint(ang * 0.5);
    float sn, cs;
    sincospif((float)r, &sn, &cs);
    return (f2){cs * scale, sn * scale};
}

// ---------------------------------------------------------------------------
// k_outer: blocks [0,cv) accumulate a private fp32 partial of the raw
// 128x128 v-tile (a,b=127 are zero pads); blocks [cv, cv+cf) accumulate a
// private 64x64 Fy partial (y folded into dim-1 phase). No atomics.
// v[a,b]  = sum_n exp(i pi x0 (a-63)) exp(i pi x1 (b-63))
// Fy[a,b] = sum_n y_n exp(-i pi x0 (a-32)) exp(-i pi x1 (b-32))
// ---------------------------------------------------------------------------
__global__ __launch_bounds__(256, 2) void k_outer(const float* __restrict__ x,
                                                  const float* __restrict__ y,
                                                  float* __restrict__ pv,
                                                  float* __restrict__ pf,
                                                  int N, int cv, int cf)
{
    __shared__ f2 hs[PB][256];
    __shared__ float xs0[PB], xs1[PB], ys[PB];

    int bx = blockIdx.x;
    int t  = threadIdx.x;
    int ty = t >> 4, tx = t & 15;

    if (bx < cv) {
        // ---------------- v path: 8x8 tile per thread, a=ty*8+i, b=tx+16*j
        int CP = (N + cv - 1) / cv;
        int n0 = bx * CP, n1 = min(N, n0 + CP);

        f2 acc[8][8];
        #pragma unroll
        for (int i = 0; i < 8; ++i)
            #pragma unroll
            for (int j = 0; j < 8; ++j) acc[i][j] = (f2){0.f, 0.f};

        for (int s = n0; s < n1; s += PB) {
            int cnt = min(PB, n1 - s);
            __syncthreads();
            if (t < cnt) {
                xs0[t] = x[2 * (s + t)];
                xs1[t] = x[2 * (s + t) + 1];
            }
            __syncthreads();
            // stage: slot t for each point; slots 0..127 = dim1, 128..255 = dim2
            for (int p = 0; p < cnt; ++p) {
                f2 g;
                if (t < 128)
                    g = (t == 127) ? (f2){0.f, 0.f} : phasef(xs0[p], (float)t - 63.f, 1.f);
                else {
                    int c = t - 128;
                    g = (c == 127) ? (f2){0.f, 0.f} : phasef(xs1[p], (float)c - 63.f, 1.f);
                }
                hs[p][t] = g;
            }
            __syncthreads();
            for (int p = 0; p < cnt; ++p) {
                f2 h1[8], h2[8], h2s[8];
                #pragma unroll
                for (int i = 0; i < 8; ++i) h1[i] = hs[p][ty * 8 + i];
                #pragma unroll
                for (int j = 0; j < 8; ++j) {
                    f2 b = hs[p][128 + tx + 16 * j];
                    h2[j] = b;
                    h2s[j] = (f2){-b.y, b.x};
                }
                #pragma unroll
                for (int i = 0; i < 8; ++i)
                    #pragma unroll
                    for (int j = 0; j < 8; ++j) {
                        acc[i][j] = acc[i][j] + f2s(h1[i].x) * h2[j];
                        acc[i][j] = acc[i][j] + f2s(h1[i].y) * h2s[j];
                    }
            }
        }
        __syncthreads();
        f2* out = (f2*)pv + (size_t)bx * 16384;
        #pragma unroll
        for (int i = 0; i < 8; ++i) {
            int a = ty * 8 + i;
            #pragma unroll
            for (int j = 0; j < 8; ++j) {
                int b = tx + 16 * j;
                out[a * 128 + b] = acc[i][j];
            }
        }
    } else {
        // ---------------- Fy path: 4x4 tile per thread, a=ty*4+i, b=tx+16*j
        int chunk = bx - cv;
        int CP = (N + cf - 1) / cf;
        int n0 = chunk * CP, n1 = min(N, n0 + CP);

        f2 acc[4][4];
        #pragma unroll
        for (int i = 0; i < 4; ++i)
            #pragma unroll
            for (int j = 0; j < 4; ++j) acc[i][j] = (f2){0.f, 0.f};

        for (int s = n0; s < n1; s += PB) {
            int cnt = min(PB, n1 - s);
            __syncthreads();
            if (t < cnt) {
                xs0[t] = x[2 * (s + t)];
                xs1[t] = x[2 * (s + t) + 1];
                ys[t]  = y[s + t];
            }
            __syncthreads();
            // 128 slots/point, 2 points per pass
            for (int p2 = 0; p2 < cnt; p2 += 2) {
                int p = p2 + (t >> 7);
                int c = t & 127;
                if (p < cnt) {
                    f2 g;
                    if (c < 64) g = phasef(xs0[p], (float)(32 - c), ys[p]);   // -(a-32)
                    else        g = phasef(xs1[p], (float)(32 - (c - 64)), 1.f);
                    hs[p][c] = g;
                }
            }
            __syncthreads();
            for (int p = 0; p < cnt; ++p) {
                f2 h1[4], h2[4], h2s[4];
                #pragma unroll
                for (int i = 0; i < 4; ++i) h1[i] = hs[p][ty * 4 + i];
                #pragma unroll
                for (int j = 0; j < 4; ++j) {
                    f2 b = hs[p][64 + tx + 16 * j];
                    h2[j] = b;
                    h2s[j] = (f2){-b.y, b.x};
                }
                #pragma unroll
                for (int i = 0; i < 4; ++i)
                    #pragma unroll
                    for (int j = 0; j < 4; ++j) {
                        acc[i][j] = acc[i][j] + f2s(h1[i].x) * h2[j];
                        acc[i][j] = acc[i][j] + f2s(h1[i].y) * h2s[j];
                    }
            }
        }
        __syncthreads();
        f2* out = (f2*)pf + (size_t)chunk * 4096;
        #pragma unroll
        for (int i = 0; i < 4; ++i) {
            int a = ty * 4 + i;
            #pragma unroll
            for (int j = 0; j < 4; ++j) {
                int b = tx + 16 * j;
                out[a * 64 + b] = acc[i][j];
            }
        }
    }
}

// ---------------------------------------------------------------------------
// k_solve (cooperative, 128 blocks x 128 threads):
//   S_A: fp64-reduce partials -> vc64 (circulant-mapped), fy -> b = ws*Fy,
//        init r=p=b, x=0, rz0.
//   S_B/S_C: 2D forward DFT of vc64 -> Vf.
//   50 x { stage1: x/r/p update + row DFT; stage2: col fwd *Vf* col inv;
//          stage3: row inv, Ap, dots (pAp, rAp, ApAp) }.
//   rz recurrence: rz+ = rz - 2a<r,Ap> + a^2|Ap|^2 (algebraically == ref).
//   Final: x += alpha_49 * p.
// ---------------------------------------------------------------------------
__global__ __launch_bounds__(128) void k_solve(
        const float* __restrict__ pv, const float* __restrict__ pf,
        const float* __restrict__ wsv, const float* __restrict__ sig2,
        double2* __restrict__ vc64, double2* __restrict__ bufA,
        double2* __restrict__ Vf, double2* __restrict__ Z1,
        double2* __restrict__ Z2, double2* __restrict__ pvec,
        double2* __restrict__ rvec, double2* __restrict__ xvec,
        double2* __restrict__ Apv, double* __restrict__ scal,
        int cv, int cf)
{
    cg::grid_group grid = cg::this_grid();
    int b = blockIdx.x, t = threadIdx.x;
    __shared__ double2 u[128], w[128], tw[128];
    __shared__ double red1[128], red2[128], red3[128];
    __shared__ double s_ab[2];

    { double sn, cs; sincospi(-(double)t / 64.0, &sn, &cs); tw[t] = make_double2(cs, sn); }

    // ---- S_A: reduce partials
    {
        int gid = b * 128 + t;
        int q1 = gid >> 7, q2 = gid & 127;
        int a = (q1 + 63) & 127, bb = (q2 + 63) & 127;
        const float* src = pv + (size_t)(a * 128 + bb) * 2;
        double sx = 0.0, sy = 0.0;
        for (int c = 0; c < cv; ++c) { sx += (double)src[0]; sy += (double)src[1]; src += 32768; }
        vc64[gid] = make_double2(sx, sy);
        if (b < 32) {
            const float* s2p = pf + (size_t)gid * 2;
            double fx = 0.0, fyv = 0.0;
            for (int c = 0; c < cf; ++c) { fx += (double)s2p[0]; fyv += (double)s2p[1]; s2p += 8192; }
            double wv = (double)wsv[gid];
            double2 bv = make_double2(wv * fx, wv * fyv);
            rvec[gid] = bv; pvec[gid] = bv; xvec[gid] = make_double2(0.0, 0.0);
            red1[t] = bv.x * bv.x + bv.y * bv.y;
            __syncthreads();
            for (int sd = 64; sd > 0; sd >>= 1) {
                if (t < sd) red1[t] += red1[t + sd];
                __syncthreads();
            }
            if (t == 0) atomicAdd(&scal[0], red1[0]);
        }
    }
    grid.sync();

    // ---- S_B: row DFT
    {
        u[t] = vc64[b * 128 + t];
        __syncthreads();
        double2 a = make_double2(0.0, 0.0);
        for (int j = 0; j < 128; ++j) dmac(a, u[j], tw[(j * t) & 127]);
        bufA[b * 128 + t] = a;
    }
    grid.sync();

    // ---- S_C: col DFT -> Vf
    {
        u[t] = bufA[t * 128 + b];
        __syncthreads();
        double2 a = make_double2(0.0, 0.0);
        for (int j = 0; j < 128; ++j) dmac(a, u[j], tw[(j * t) & 127]);
        Vf[t * 128 + b] = a;
    }
    grid.sync();

    // ---- CG loop
    for (int it = 0; it < 50; ++it) {
        // stage1 (rows)
        if (b < 64) {
            if (it > 0 && t == 0) {
                double rz = scal[0], alpha_p = 0.0, rz_p = rz;
                for (int k = 0; k < it; ++k) {
                    double pap = scal[1 + 3 * k], rap = scal[2 + 3 * k], apap = scal[3 + 3 * k];
                    double al = rz / (pap + 1e-30);
                    double rzn = fma(al, fma(al, apap, -2.0 * rap), rz);
                    if (k == it - 1) { alpha_p = al; rz_p = rz; }
                    rz = rzn;
                }
                s_ab[0] = alpha_p;
                s_ab[1] = rz / (rz_p + 1e-30);   // beta_it
            }
            __syncthreads();
            if (t < 64) {
                int idx = b * 64 + t;
                double2 pvv;
                if (it == 0) {
                    pvv = pvec[idx];
                } else {
                    double alpha = s_ab[0], beta = s_ab[1];
                    double2 po = pvec[idx], ap = Apv[idx];
                    double2 xv = xvec[idx], rv = rvec[idx];
                    xv.x += alpha * po.x; xv.y += alpha * po.y;
                    rv.x -= alpha * ap.x; rv.y -= alpha * ap.y;
                    xvec[idx] = xv; rvec[idx] = rv;
                    pvv = make_double2(rv.x + beta * po.x, rv.y + beta * po.y);
                    pvec[idx] = pvv;
                }
                double wv = (double)wsv[idx];
                u[t] = make_double2(wv * pvv.x, wv * pvv.y);
            } else {
                u[t] = make_double2(0.0, 0.0);
            }
            __syncthreads();
            double2 a = make_double2(0.0, 0.0);
            for (int j = 0; j < 64; ++j) dmac(a, u[j], tw[(j * t) & 127]);
            Z1[b * 128 + t] = a;
        }
        grid.sync();

        // stage2 (cols)
        {
            int c = b;
            if (t < 64) u[t] = Z1[t * 128 + c];
            __syncthreads();
            double2 a = make_double2(0.0, 0.0);
            for (int j = 0; j < 64; ++j) dmac(a, u[j], tw[(j * t) & 127]);
            double2 vf = Vf[t * 128 + c];
            w[t] = make_double2(a.x * vf.x - a.y * vf.y, a.x * vf.y + a.y * vf.x);
            __syncthreads();
            if (t < 64) {
                double2 a2 = make_double2(0.0, 0.0);
                for (int m = 0; m < 128; ++m) dmacc(a2, w[m], tw[(t * m) & 127]);
                Z2[t * 128 + c] = a2;
            }
        }
        grid.sync();

        // stage3 (rows): inv row DFT, Ap, dots
        if (b < 64) {
            w[t] = Z2[b * 128 + t];
            __syncthreads();
            double d1 = 0.0, d2 = 0.0, d3 = 0.0;
            if (t < 64) {
                double2 a = make_double2(0.0, 0.0);
                for (int m = 0; m < 128; ++m) dmacc(a, w[m], tw[(t * m) & 127]);
                int idx = b * 64 + t;
                double wv = (double)wsv[idx], s2 = (double)sig2[0];
                double2 pp = pvec[idx], rr = rvec[idx];
                double2 ap = make_double2(wv * a.x * (1.0 / 16384.0) + s2 * pp.x,
                                          wv * a.y * (1.0 / 16384.0) + s2 * pp.y);
                Apv[idx] = ap;
                d1 = pp.x * ap.x + pp.y * ap.y;
                d2 = rr.x * ap.x + rr.y * ap.y;
                d3 = ap.x * ap.x + ap.y * ap.y;
            }
            red1[t] = d1; red2[t] = d2; red3[t] = d3;
            __syncthreads();
            for (int sd = 64; sd > 0; sd >>= 1) {
                if (t < sd) { red1[t] += red1[t + sd]; red2[t] += red2[t + sd]; red3[t] += red3[t + sd]; }
                __syncthreads();
            }
            if (t == 0) {
                atomicAdd(&scal[1 + 3 * it], red1[0]);
                atomicAdd(&scal[2 + 3 * it], red2[0]);
                atomicAdd(&scal[3 + 3 * it], red3[0]);
            }
        }
        grid.sync();
    }

    // ---- final: x += alpha_49 * p
    if (b < 64 && t < 64) {
        double rz = scal[0], alpha_l = 0.0;
        for (int k = 0; k < 50; ++k) {
            double pap = scal[1 + 3 * k], rap = scal[2 + 3 * k], apap = scal[3 + 3 * k];
            double al = rz / (pap + 1e-30);
            if (k == 49) alpha_l = al;
            rz = fma(al, fma(al, apap, -2.0 * rap), rz);
        }
        int idx = b * 64 + t;
        double2 po = pvec[idx], xv = xvec[idx];
        xv.x += alpha_l * po.x; xv.y += alpha_l * po.y;
        xvec[idx] = xv;
    }
}

// ---------------------------------------------------------------------------
// Evaluation: mu[b] = Re( sum_j e1[j] * sum_k alpha[j,k] e2[k] ),
// alpha = ws*xsol (fp32 in LDS); phases via fp64 sincospi/recurrence.
// ---------------------------------------------------------------------------
__global__ __launch_bounds__(64) void k_eval(const float* __restrict__ xnew,
                                             const float* __restrict__ wsv,
                                             const double2* __restrict__ xsol,
                                             float* __restrict__ out, int B)
{
    __shared__ float2 al[4096];
    int t = threadIdx.x;
    int b = blockIdx.x * 64 + t;
    for (int i = t; i < 4096; i += 64) {
        double2 xv = xsol[i];
        double w = (double)wsv[i];
        al[i] = make_float2((float)(w * xv.x), (float)(w * xv.y));
    }
    float x0 = 0.f, x1 = 0.f;
    if (b < B) { x0 = xnew[2 * b]; x1 = xnew[2 * b + 1]; }
    __syncthreads();
    double2 wstep; { double sn, cs; sincospi((double)x1, &sn, &cs); wstep = make_double2(cs, sn); }
    double mu = 0.0;
    for (int jg = 0; jg < 4; ++jg) {
        float2 tacc[16];
        for (int q = 0; q < 16; ++q) tacc[q] = make_float2(0.f, 0.f);
        double2 e2; { double sn, cs; sincospi(-32.0 * (double)x1, &sn, &cs); e2 = make_double2(cs, sn); }
        for (int k = 0; k < 64; ++k) {
            float2 e2f = make_float2((float)e2.x, (float)e2.y);
            for (int q = 0; q < 16; ++q) {
                int j = jg * 16 + q;
                float2 a = al[j * 64 + k];
                tacc[q].x += a.x * e2f.x - a.y * e2f.y;
                tacc[q].y += a.x * e2f.y + a.y * e2f.x;
            }
            e2 = make_double2(e2.x * wstep.x - e2.y * wstep.y,
                              e2.x * wstep.y + e2.y * wstep.x);
        }
        for (int q = 0; q < 16; ++q) {
            int j = jg * 16 + q;
            double sn, cs;
            sincospi((double)x0 * (double)(j - 32), &sn, &cs);
            mu += cs * (double)tacc[q].x - sn * (double)tacc[q].y;
        }
    }
    if (b < B) out[b] = (float)mu;
}

// ---------------------------------------------------------------------------

extern "C" void kernel_launch(void* const* d_in, const int* in_sizes, int n_in,
                              void* d_out, int out_size, void* d_ws, size_t ws_size,
                              hipStream_t stream)
{
    const float* x    = (const float*)d_in[0];
    const float* y    = (const float*)d_in[1];
    const float* xnew = (const float*)d_in[2];
    const float* wsv  = (const float*)d_in[3];
    const float* sig2 = (const float*)d_in[4];
    int N = in_sizes[1];
    int B = in_sizes[2] / 2;

    char* base = (char*)d_ws;
    size_t o = 0;
    double2* vc64 = (double2*)(base + o); o += 262144;
    double2* bufA = (double2*)(base + o); o += 262144;
    double2* Vf   = (double2*)(base + o); o += 262144;
    double2* Z1   = (double2*)(base + o); o += 131072;
    double2* Z2   = (double2*)(base + o); o += 131072;
    double2* pvec = (double2*)(base + o); o += 65536;
    double2* rvec = (double2*)(base + o); o += 65536;
    double2* xvec = (double2*)(base + o); o += 65536;
    double2* Apv  = (double2*)(base + o); o += 65536;
    double*  scal = (double*)(base + o);  o += 4096;
    // runtime-sized partial buffers (cv v-chunks of 128 KiB, cf=cv/4 Fy of 32 KiB)
    size_t avail = (ws_size > o) ? ws_size - o : 0;
    int cv = (int)(avail / 139264);       // 131072 + 32768/4 per cv unit
    if (cv > 384) cv = 384;
    if (cv < 4) cv = 4;
    cv &= ~3;
    int cf = cv / 4;
    float* pv = (float*)(base + o); o += (size_t)cv * 131072;
    float* pf = (float*)(base + o);

    hipMemsetAsync(scal, 0, 4096, stream);

    k_outer<<<cv + cf, 256, 0, stream>>>(x, y, pv, pf, N, cv, cf);

    void* args[] = { (void*)&pv, (void*)&pf, (void*)&wsv, (void*)&sig2,
                     (void*)&vc64, (void*)&bufA, (void*)&Vf, (void*)&Z1,
                     (void*)&Z2, (void*)&pvec, (void*)&rvec, (void*)&xvec,
                     (void*)&Apv, (void*)&scal, (void*)&cv, (void*)&cf };
    hipLaunchCooperativeKernel((void*)k_solve, dim3(128), dim3(128), args, 0, stream);

    k_eval<<<(B + 63) / 64, 64, 0, stream>>>(xnew, wsv, xvec, (float*)d_out, B);
}

// Round 4
// 2140.759 us; speedup vs baseline: 1.6484x; 1.6484x over previous
//
#include <hip/hip_runtime.h>
#include <math.h>

// ---------------------------------------------------------------------------
// GP posterior mean: separable NUFFT outer products (fp32 atomic-free
// partials) -> fp64 reduce to raw Toeplitz table vR -> 50 x fused CG
// iteration kernels (direct Toeplitz MV, row-parallel, double-buffered
// state; replicated elementwise update per block) -> eval.
// No FFTs, no grid syncs: 1 launch per CG iteration.
// ---------------------------------------------------------------------------

typedef float f2 __attribute__((ext_vector_type(2)));
#define PB 16

__device__ inline f2 f2s(float s) { return (f2){s, s}; }

__device__ inline void dmac(double2& acc, double2 a, double2 b) {
    acc.x = fma(a.x, b.x, fma(-a.y, b.y, acc.x));
    acc.y = fma(a.x, b.y, fma(a.y, b.x, acc.y));
}

// exp(i*pi*x*m) with fp64 angle reduction, scaled
__device__ inline f2 phasef(float xv, float m, float scale) {
    double ang = (double)xv * (double)m;
    double r = ang - 2.0 * rint(ang * 0.5);
    float sn, cs;
    sincospif((float)r, &sn, &cs);
    return (f2){cs * scale, sn * scale};
}

// ---------------------------------------------------------------------------
// k_outer: blocks [0,cv) accumulate a private fp32 partial of the raw
// 128x128 v-tile (a,b=127 zero pads); blocks [cv,cv+cf) a private 64x64 Fy
// partial (y folded into dim-1 phase). No atomics.
// v[a,b]  = sum_n exp(i pi x0 (a-63)) exp(i pi x1 (b-63)),  a,b in [0,126]
// Fy[a,b] = sum_n y_n exp(-i pi x0 (a-32)) exp(-i pi x1 (b-32))
// ---------------------------------------------------------------------------
__global__ __launch_bounds__(256, 2) void k_outer(const float* __restrict__ x,
                                                  const float* __restrict__ y,
                                                  float* __restrict__ pv,
                                                  float* __restrict__ pf,
                                                  int N, int cv, int cf)
{
    __shared__ f2 hs[PB][256];
    __shared__ float xs0[PB], xs1[PB], ys[PB];

    int bx = blockIdx.x;
    int t  = threadIdx.x;
    int ty = t >> 4, tx = t & 15;

    if (bx < cv) {
        int CP = (N + cv - 1) / cv;
        int n0 = bx * CP, n1 = min(N, n0 + CP);

        f2 acc[8][8];
        #pragma unroll
        for (int i = 0; i < 8; ++i)
            #pragma unroll
            for (int j = 0; j < 8; ++j) acc[i][j] = (f2){0.f, 0.f};

        for (int s = n0; s < n1; s += PB) {
            int cnt = min(PB, n1 - s);
            __syncthreads();
            if (t < cnt) {
                xs0[t] = x[2 * (s + t)];
                xs1[t] = x[2 * (s + t) + 1];
            }
            __syncthreads();
            for (int p = 0; p < cnt; ++p) {
                f2 g;
                if (t < 128)
                    g = (t == 127) ? (f2){0.f, 0.f} : phasef(xs0[p], (float)t - 63.f, 1.f);
                else {
                    int c = t - 128;
                    g = (c == 127) ? (f2){0.f, 0.f} : phasef(xs1[p], (float)c - 63.f, 1.f);
                }
                hs[p][t] = g;
            }
            __syncthreads();
            for (int p = 0; p < cnt; ++p) {
                f2 h1[8], h2[8], h2s[8];
                #pragma unroll
                for (int i = 0; i < 8; ++i) h1[i] = hs[p][ty * 8 + i];
                #pragma unroll
                for (int j = 0; j < 8; ++j) {
                    f2 b = hs[p][128 + tx + 16 * j];
                    h2[j] = b;
                    h2s[j] = (f2){-b.y, b.x};
                }
                #pragma unroll
                for (int i = 0; i < 8; ++i)
                    #pragma unroll
                    for (int j = 0; j < 8; ++j) {
                        acc[i][j] = acc[i][j] + f2s(h1[i].x) * h2[j];
                        acc[i][j] = acc[i][j] + f2s(h1[i].y) * h2s[j];
                    }
            }
        }
        __syncthreads();
        f2* out = (f2*)pv + (size_t)bx * 16384;
        #pragma unroll
        for (int i = 0; i < 8; ++i) {
            int a = ty * 8 + i;
            #pragma unroll
            for (int j = 0; j < 8; ++j) {
                int b = tx + 16 * j;
                out[a * 128 + b] = acc[i][j];
            }
        }
    } else {
        int chunk = bx - cv;
        int CP = (N + cf - 1) / cf;
        int n0 = chunk * CP, n1 = min(N, n0 + CP);

        f2 acc[4][4];
        #pragma unroll
        for (int i = 0; i < 4; ++i)
            #pragma unroll
            for (int j = 0; j < 4; ++j) acc[i][j] = (f2){0.f, 0.f};

        for (int s = n0; s < n1; s += PB) {
            int cnt = min(PB, n1 - s);
            __syncthreads();
            if (t < cnt) {
                xs0[t] = x[2 * (s + t)];
                xs1[t] = x[2 * (s + t) + 1];
                ys[t]  = y[s + t];
            }
            __syncthreads();
            for (int p2 = 0; p2 < cnt; p2 += 2) {
                int p = p2 + (t >> 7);
                int c = t & 127;
                if (p < cnt) {
                    f2 g;
                    if (c < 64) g = phasef(xs0[p], (float)(32 - c), ys[p]);
                    else        g = phasef(xs1[p], (float)(32 - (c - 64)), 1.f);
                    hs[p][c] = g;
                }
            }
            __syncthreads();
            for (int p = 0; p < cnt; ++p) {
                f2 h1[4], h2[4], h2s[4];
                #pragma unroll
                for (int i = 0; i < 4; ++i) h1[i] = hs[p][ty * 4 + i];
                #pragma unroll
                for (int j = 0; j < 4; ++j) {
                    f2 b = hs[p][64 + tx + 16 * j];
                    h2[j] = b;
                    h2s[j] = (f2){-b.y, b.x};
                }
                #pragma unroll
                for (int i = 0; i < 4; ++i)
                    #pragma unroll
                    for (int j = 0; j < 4; ++j) {
                        acc[i][j] = acc[i][j] + f2s(h1[i].x) * h2[j];
                        acc[i][j] = acc[i][j] + f2s(h1[i].y) * h2s[j];
                    }
            }
        }
        __syncthreads();
        f2* out = (f2*)pf + (size_t)chunk * 4096;
        #pragma unroll
        for (int i = 0; i < 4; ++i) {
            int a = ty * 4 + i;
            #pragma unroll
            for (int j = 0; j < 4; ++j) {
                int b = tx + 16 * j;
                out[a * 64 + b] = acc[i][j];
            }
        }
    }
}

// ---------------------------------------------------------------------------
// k_reduce: fp64-reduce v partials into vR[(d1+64)*128 + (d2+64)] (natural
// Toeplitz layout, row/col 0 = zero pad) and Fy partials into b = ws*Fy;
// init r0 = p0 = b, x0 = 0, scal[0] = <b,b>.
// ---------------------------------------------------------------------------
__global__ __launch_bounds__(128) void k_reduce(const float* __restrict__ pv,
                                                const float* __restrict__ pf,
                                                const float* __restrict__ wsv,
                                                double2* __restrict__ vR,
                                                double2* __restrict__ r0,
                                                double2* __restrict__ p0,
                                                double2* __restrict__ x0,
                                                double* __restrict__ scal,
                                                int cv, int cf)
{
    int gid = blockIdx.x * 128 + threadIdx.x;   // 0..16383
    int q1 = gid >> 7, q2 = gid & 127;
    double sx = 0.0, sy = 0.0;
    if (q1 >= 1 && q2 >= 1) {
        const float* src = pv + (size_t)((q1 - 1) * 128 + (q2 - 1)) * 2;
        for (int c = 0; c < cv; ++c) { sx += (double)src[0]; sy += (double)src[1]; src += 32768; }
    }
    vR[gid] = make_double2(sx, sy);
    if (gid < 4096) {
        const float* s2p = pf + (size_t)gid * 2;
        double fx = 0.0, fy2 = 0.0;
        for (int c = 0; c < cf; ++c) { fx += (double)s2p[0]; fy2 += (double)s2p[1]; s2p += 8192; }
        double w = (double)wsv[gid];
        double2 bv = make_double2(w * fx, w * fy2);
        r0[gid] = bv; p0[gid] = bv; x0[gid] = make_double2(0.0, 0.0);
        double rr = bv.x * bv.x + bv.y * bv.y;
        for (int off = 32; off > 0; off >>= 1) rr += __shfl_down(rr, off);
        if ((threadIdx.x & 63) == 0) atomicAdd(&scal[0], rr);
    }
}

// ---------------------------------------------------------------------------
// k_cg_iter: one full CG iteration, 256 blocks x 256 threads, row-parallel.
//   scalars: recompute alpha_{it-1}, beta_it from dot history (scal).
//   update (replicated per block): z = ws * p_it into LDS (r_it, p_it formed
//     on the fly from parity-in buffers).
//   MV: rows k = b*16 + rq*4 + i (rq = t>>6, i=0..3), cols j1 = t&63 fixed,
//     j2 = 0..63 inner with 4-wide sliding v-window; wave-reduce 64 lanes.
//   lane 0 writes Ap/r/p/x slices (parity-out) + dot partials -> scal.
//   scal layout: [0] = rz0; [1+3k..3+3k] = (pAp, rAp, ApAp) of iter k.
// ---------------------------------------------------------------------------
__global__ __launch_bounds__(256) void k_cg_iter(
        const double2* __restrict__ vR, const float* __restrict__ wsv,
        const float* __restrict__ sig2,
        const double2* __restrict__ pin, double2* __restrict__ pout,
        const double2* __restrict__ rin, double2* __restrict__ rout,
        const double2* __restrict__ xin, double2* __restrict__ xout,
        const double2* __restrict__ apin, double2* __restrict__ apout,
        double* __restrict__ scal, int it)
{
    __shared__ double2 zs[4096];
    __shared__ double s_ab[2];
    __shared__ double redd[4][3];
    int b = blockIdx.x, t = threadIdx.x;

    if (t == 0) {
        double alpha = 0.0, beta = 0.0;
        if (it > 0) {
            double rz = scal[0], rzp = rz, alp = 0.0;
            for (int k = 0; k < it; ++k) {
                double pap = scal[1 + 3 * k], rap = scal[2 + 3 * k], apap = scal[3 + 3 * k];
                double al = rz / (pap + 1e-30);
                rzp = rz; alp = al;
                rz = fma(al, fma(al, apap, -2.0 * rap), rz);
            }
            alpha = alp; beta = rz / (rzp + 1e-30);
        }
        s_ab[0] = alpha; s_ab[1] = beta;
    }
    __syncthreads();
    double alpha = s_ab[0], beta = s_ab[1];

    // replicated update: z = ws * p_new
    for (int s = 0; s < 16; ++s) {
        int i = t + 256 * s;
        double2 rv = rin[i];
        if (it > 0) {
            double2 ap = apin[i];
            rv.x -= alpha * ap.x; rv.y -= alpha * ap.y;
        }
        double2 pv = pin[i];
        double2 pn = make_double2(rv.x + beta * pv.x, rv.y + beta * pv.y);
        double w = (double)wsv[i];
        zs[i] = make_double2(w * pn.x, w * pn.y);
    }
    __syncthreads();

    // direct Toeplitz MV
    int rq = t >> 6, j1 = t & 63;
    int k1 = b >> 2;
    int k2b = (b & 3) * 16 + rq * 4;
    const double2* vrow = vR + (k1 - j1 + 64) * 128;
    int q0 = k2b + 64;
    double2 vw[4], acc[4];
    #pragma unroll
    for (int i = 0; i < 4; ++i) { vw[i] = vrow[q0 + i]; acc[i] = make_double2(0.0, 0.0); }
    const double2* zp = zs + j1 * 64;
    #pragma unroll 4
    for (int j2 = 0; j2 < 64; ++j2) {
        double2 zj = zp[j2];
        #pragma unroll
        for (int i = 0; i < 4; ++i) dmac(acc[i], vw[i], zj);
        vw[3] = vw[2]; vw[2] = vw[1]; vw[1] = vw[0];
        vw[0] = vrow[q0 - j2 - 1];
    }

    #pragma unroll
    for (int off = 32; off > 0; off >>= 1)
        #pragma unroll
        for (int i = 0; i < 4; ++i) {
            acc[i].x += __shfl_down(acc[i].x, off);
            acc[i].y += __shfl_down(acc[i].y, off);
        }

    if (j1 == 0) {
        double s2 = (double)sig2[0];
        double d1 = 0.0, d2 = 0.0, d3 = 0.0;
        #pragma unroll
        for (int i = 0; i < 4; ++i) {
            int k = b * 16 + rq * 4 + i;
            double2 rv = rin[k];
            if (it > 0) {
                double2 ap = apin[k];
                rv.x -= alpha * ap.x; rv.y -= alpha * ap.y;
            }
            double2 pv = pin[k];
            double2 pn = make_double2(rv.x + beta * pv.x, rv.y + beta * pv.y);
            double w = (double)wsv[k];
            double2 apn = make_double2(w * acc[i].x + s2 * pn.x,
                                       w * acc[i].y + s2 * pn.y);
            apout[k] = apn; rout[k] = rv; pout[k] = pn;
            double2 xv = xin[k];
            xout[k] = make_double2(xv.x + alpha * pv.x, xv.y + alpha * pv.y);
            d1 += pn.x * apn.x + pn.y * apn.y;
            d2 += rv.x * apn.x + rv.y * apn.y;
            d3 += apn.x * apn.x + apn.y * apn.y;
        }
        redd[rq][0] = d1; redd[rq][1] = d2; redd[rq][2] = d3;
    }
    __syncthreads();
    if (t == 0) {
        double a = 0.0, bb = 0.0, c = 0.0;
        for (int q = 0; q < 4; ++q) { a += redd[q][0]; bb += redd[q][1]; c += redd[q][2]; }
        atomicAdd(&scal[1 + 3 * it], a);
        atomicAdd(&scal[2 + 3 * it], bb);
        atomicAdd(&scal[3 + 3 * it], c);
    }
}

// ---------------------------------------------------------------------------
// k_eval: mu[b] = Re( sum_j e1[j] * sum_k alpha[j,k] e2[k] ),
// alpha = ws * (x_49 + alpha_49 * p_49)  (final CG update folded in).
// ---------------------------------------------------------------------------
__global__ __launch_bounds__(64) void k_eval(const float* __restrict__ xnew,
                                             const float* __restrict__ wsv,
                                             const double2* __restrict__ xsol,
                                             const double2* __restrict__ psol,
                                             const double* __restrict__ scal,
                                             float* __restrict__ out, int B)
{
    __shared__ float2 al[4096];
    __shared__ double s_al;
    int t = threadIdx.x;
    int b = blockIdx.x * 64 + t;
    if (t == 0) {
        double rz = scal[0], alp = 0.0;
        for (int k = 0; k < 50; ++k) {
            double pap = scal[1 + 3 * k], rap = scal[2 + 3 * k], apap = scal[3 + 3 * k];
            double a2 = rz / (pap + 1e-30);
            alp = a2;
            rz = fma(a2, fma(a2, apap, -2.0 * rap), rz);
        }
        s_al = alp;
    }
    __syncthreads();
    double alpha49 = s_al;
    for (int i = t; i < 4096; i += 64) {
        double2 xv = xsol[i];
        double2 pv = psol[i];
        double w = (double)wsv[i];
        al[i] = make_float2((float)(w * (xv.x + alpha49 * pv.x)),
                            (float)(w * (xv.y + alpha49 * pv.y)));
    }
    float x0 = 0.f, x1 = 0.f;
    if (b < B) { x0 = xnew[2 * b]; x1 = xnew[2 * b + 1]; }
    __syncthreads();
    double2 wstep; { double sn, cs; sincospi((double)x1, &sn, &cs); wstep = make_double2(cs, sn); }
    double mu = 0.0;
    for (int jg = 0; jg < 4; ++jg) {
        float2 tacc[16];
        for (int q = 0; q < 16; ++q) tacc[q] = make_float2(0.f, 0.f);
        double2 e2; { double sn, cs; sincospi(-32.0 * (double)x1, &sn, &cs); e2 = make_double2(cs, sn); }
        for (int k = 0; k < 64; ++k) {
            float2 e2f = make_float2((float)e2.x, (float)e2.y);
            for (int q = 0; q < 16; ++q) {
                int j = jg * 16 + q;
                float2 a = al[j * 64 + k];
                tacc[q].x += a.x * e2f.x - a.y * e2f.y;
                tacc[q].y += a.x * e2f.y + a.y * e2f.x;
            }
            e2 = make_double2(e2.x * wstep.x - e2.y * wstep.y,
                              e2.x * wstep.y + e2.y * wstep.x);
        }
        for (int q = 0; q < 16; ++q) {
            int j = jg * 16 + q;
            double sn, cs;
            sincospi((double)x0 * (double)(j - 32), &sn, &cs);
            mu += cs * (double)tacc[q].x - sn * (double)tacc[q].y;
        }
    }
    if (b < B) out[b] = (float)mu;
}

// ---------------------------------------------------------------------------

extern "C" void kernel_launch(void* const* d_in, const int* in_sizes, int n_in,
                              void* d_out, int out_size, void* d_ws, size_t ws_size,
                              hipStream_t stream)
{
    const float* x    = (const float*)d_in[0];
    const float* y    = (const float*)d_in[1];
    const float* xnew = (const float*)d_in[2];
    const float* wsv  = (const float*)d_in[3];
    const float* sig2 = (const float*)d_in[4];
    int N = in_sizes[1];
    int B = in_sizes[2] / 2;

    char* base = (char*)d_ws;
    size_t o = 0;
    double2* vR = (double2*)(base + o); o += 262144;     // 128x128 Toeplitz table
    double2* rb[2], *pb[2], *xb[2], *ab[2];
    for (int q = 0; q < 2; ++q) { rb[q] = (double2*)(base + o); o += 65536; }
    for (int q = 0; q < 2; ++q) { pb[q] = (double2*)(base + o); o += 65536; }
    for (int q = 0; q < 2; ++q) { xb[q] = (double2*)(base + o); o += 65536; }
    for (int q = 0; q < 2; ++q) { ab[q] = (double2*)(base + o); o += 65536; }
    double* scal = (double*)(base + o); o += 4096;       // [0]=rz0, then 50 triples
    size_t avail = (ws_size > o) ? ws_size - o : 0;
    int cv = (int)(avail / 139264);                      // 128KB v + 8KB fy per unit
    if (cv > 384) cv = 384;
    if (cv < 4) cv = 4;
    cv &= ~3;
    int cf = cv / 4;
    float* pv = (float*)(base + o); o += (size_t)cv * 131072;
    float* pf = (float*)(base + o);

    hipMemsetAsync(scal, 0, 4096, stream);

    k_outer<<<cv + cf, 256, 0, stream>>>(x, y, pv, pf, N, cv, cf);
    k_reduce<<<128, 128, 0, stream>>>(pv, pf, wsv, vR, rb[0], pb[0], xb[0], scal, cv, cf);

    for (int it = 0; it < 50; ++it) {
        int in = it & 1, op = in ^ 1;
        k_cg_iter<<<256, 256, 0, stream>>>(vR, wsv, sig2,
                                           pb[in], pb[op], rb[in], rb[op],
                                           xb[in], xb[op], ab[in], ab[op],
                                           scal, it);
    }
    // after it=49: final state (x_49, p_49) in parity-0 buffers
    k_eval<<<(B + 63) / 64, 64, 0, stream>>>(xnew, wsv, xb[0], pb[0], scal,
                                             (float*)d_out, B);
}

// Round 5
// 2040.479 us; speedup vs baseline: 1.7294x; 1.0491x over previous
//
#include <hip/hip_runtime.h>
#include <math.h>

// ---------------------------------------------------------------------------
// GP posterior mean: separable NUFFT outer products (fp32 atomic-free
// partials) -> sliced fp64 reduce to Toeplitz table vR -> 50 x fused CG
// iteration kernels (direct Toeplitz MV, lane=j2 coalesced, double-buffered
// state) -> eval. 1 launch per CG iteration.
// ---------------------------------------------------------------------------

typedef float f2 __attribute__((ext_vector_type(2)));
#define PB 16

__device__ inline f2 f2s(float s) { return (f2){s, s}; }

__device__ inline void dmac(double2& acc, double2 a, double2 b) {
    acc.x = fma(a.x, b.x, fma(-a.y, b.y, acc.x));
    acc.y = fma(a.x, b.y, fma(a.y, b.x, acc.y));
}

// exp(i*pi*x*m) with fp64 angle reduction, scaled
__device__ inline f2 phasef(float xv, float m, float scale) {
    double ang = (double)xv * (double)m;
    double r = ang - 2.0 * rint(ang * 0.5);
    float sn, cs;
    sincospif((float)r, &sn, &cs);
    return (f2){cs * scale, sn * scale};
}

// ---------------------------------------------------------------------------
// k_outer: blocks [0,cv) accumulate a private fp32 partial of the raw
// 128x128 v-tile (a,b=127 zero pads); blocks [cv,cv+cf) a private 64x64 Fy
// partial (y folded into dim-1 phase). No atomics. Thread tiles are
// LDS-contiguous in both dims (b128-friendly).
// v[a,b]  = sum_n exp(i pi x0 (a-63)) exp(i pi x1 (b-63)),  a,b in [0,126]
// Fy[a,b] = sum_n y_n exp(-i pi x0 (a-32)) exp(-i pi x1 (b-32))
// ---------------------------------------------------------------------------
__global__ __launch_bounds__(256, 2) void k_outer(const float* __restrict__ x,
                                                  const float* __restrict__ y,
                                                  float* __restrict__ pv,
                                                  float* __restrict__ pf,
                                                  int N, int cv, int cf)
{
    __shared__ f2 hs[PB][256];
    __shared__ float xs0[PB], xs1[PB], ys[PB];

    int bx = blockIdx.x;
    int t  = threadIdx.x;
    int ty = t >> 4, tx = t & 15;

    if (bx < cv) {
        int CP = (N + cv - 1) / cv;
        int n0 = bx * CP, n1 = min(N, n0 + CP);

        f2 acc[8][8];
        #pragma unroll
        for (int i = 0; i < 8; ++i)
            #pragma unroll
            for (int j = 0; j < 8; ++j) acc[i][j] = (f2){0.f, 0.f};

        for (int s = n0; s < n1; s += PB) {
            int cnt = min(PB, n1 - s);
            __syncthreads();
            if (t < cnt) {
                xs0[t] = x[2 * (s + t)];
                xs1[t] = x[2 * (s + t) + 1];
            }
            __syncthreads();
            for (int p = 0; p < cnt; ++p) {
                f2 g;
                if (t < 128)
                    g = (t == 127) ? (f2){0.f, 0.f} : phasef(xs0[p], (float)t - 63.f, 1.f);
                else {
                    int c = t - 128;
                    g = (c == 127) ? (f2){0.f, 0.f} : phasef(xs1[p], (float)c - 63.f, 1.f);
                }
                hs[p][t] = g;
            }
            __syncthreads();
            for (int p = 0; p < cnt; ++p) {
                f2 h1[8], h2[8], h2s[8];
                #pragma unroll
                for (int i = 0; i < 8; ++i) h1[i] = hs[p][ty * 8 + i];
                #pragma unroll
                for (int j = 0; j < 8; ++j) {
                    f2 b = hs[p][128 + tx * 8 + j];
                    h2[j] = b;
                    h2s[j] = (f2){-b.y, b.x};
                }
                #pragma unroll
                for (int i = 0; i < 8; ++i)
                    #pragma unroll
                    for (int j = 0; j < 8; ++j) {
                        acc[i][j] = acc[i][j] + f2s(h1[i].x) * h2[j];
                        acc[i][j] = acc[i][j] + f2s(h1[i].y) * h2s[j];
                    }
            }
        }
        __syncthreads();
        f2* out = (f2*)pv + (size_t)bx * 16384;
        #pragma unroll
        for (int i = 0; i < 8; ++i) {
            int a = ty * 8 + i;
            #pragma unroll
            for (int j = 0; j < 8; ++j)
                out[a * 128 + tx * 8 + j] = acc[i][j];
        }
    } else {
        int chunk = bx - cv;
        int CP = (N + cf - 1) / cf;
        int n0 = chunk * CP, n1 = min(N, n0 + CP);

        f2 acc[4][4];
        #pragma unroll
        for (int i = 0; i < 4; ++i)
            #pragma unroll
            for (int j = 0; j < 4; ++j) acc[i][j] = (f2){0.f, 0.f};

        for (int s = n0; s < n1; s += PB) {
            int cnt = min(PB, n1 - s);
            __syncthreads();
            if (t < cnt) {
                xs0[t] = x[2 * (s + t)];
                xs1[t] = x[2 * (s + t) + 1];
                ys[t]  = y[s + t];
            }
            __syncthreads();
            for (int p2 = 0; p2 < cnt; p2 += 2) {
                int p = p2 + (t >> 7);
                int c = t & 127;
                if (p < cnt) {
                    f2 g;
                    if (c < 64) g = phasef(xs0[p], (float)(32 - c), ys[p]);
                    else        g = phasef(xs1[p], (float)(32 - (c - 64)), 1.f);
                    hs[p][c] = g;
                }
            }
            __syncthreads();
            for (int p = 0; p < cnt; ++p) {
                f2 h1[4], h2[4], h2s[4];
                #pragma unroll
                for (int i = 0; i < 4; ++i) h1[i] = hs[p][ty * 4 + i];
                #pragma unroll
                for (int j = 0; j < 4; ++j) {
                    f2 b = hs[p][64 + tx * 4 + j];
                    h2[j] = b;
                    h2s[j] = (f2){-b.y, b.x};
                }
                #pragma unroll
                for (int i = 0; i < 4; ++i)
                    #pragma unroll
                    for (int j = 0; j < 4; ++j) {
                        acc[i][j] = acc[i][j] + f2s(h1[i].x) * h2[j];
                        acc[i][j] = acc[i][j] + f2s(h1[i].y) * h2s[j];
                    }
            }
        }
        __syncthreads();
        f2* out = (f2*)pf + (size_t)chunk * 4096;
        #pragma unroll
        for (int i = 0; i < 4; ++i) {
            int a = ty * 4 + i;
            #pragma unroll
            for (int j = 0; j < 4; ++j)
                out[a * 64 + tx * 4 + j] = acc[i][j];
        }
    }
}

// ---------------------------------------------------------------------------
// k_reduce: v partials sliced 8-way per element -> fp64 atomicAdd into
// vR[(d1+64)*128 + (d2+64)] (zero-initialized; row/col 0 = pads). Fy
// partials serial per element -> b = ws*Fy, init r0=p0=b, x0=0, rz0.
// Thread space: [0,131072) = v (elem = id>>3, slice = id&7);
//               [131072,135168) = Fy.
// ---------------------------------------------------------------------------
__global__ __launch_bounds__(256) void k_reduce(const float* __restrict__ pv,
                                                const float* __restrict__ pf,
                                                const float* __restrict__ wsv,
                                                double* __restrict__ vRd,
                                                double2* __restrict__ r0,
                                                double2* __restrict__ p0,
                                                double2* __restrict__ x0,
                                                double* __restrict__ scal,
                                                int cv, int cf)
{
    int id = blockIdx.x * 256 + threadIdx.x;
    if (id < 131072) {
        int e = id >> 3, sl = id & 7;
        int q1 = e >> 7, q2 = e & 127;
        if (q1 >= 1 && q2 >= 1) {
            int cn = cv >> 3;
            const float* src = pv + (size_t)((q1 - 1) * 128 + (q2 - 1)) * 2
                                  + (size_t)(sl * cn) * 32768;
            double sx = 0.0, sy = 0.0;
            for (int c = 0; c < cn; ++c) { sx += (double)src[0]; sy += (double)src[1]; src += 32768; }
            atomicAdd(&vRd[e * 2], sx);
            atomicAdd(&vRd[e * 2 + 1], sy);
        }
    } else {
        int e = id - 131072;          // 0..4095
        const float* s2p = pf + (size_t)e * 2;
        double fx = 0.0, fy2 = 0.0;
        for (int c = 0; c < cf; ++c) { fx += (double)s2p[0]; fy2 += (double)s2p[1]; s2p += 8192; }
        double w = (double)wsv[e];
        double2 bv = make_double2(w * fx, w * fy2);
        r0[e] = bv; p0[e] = bv; x0[e] = make_double2(0.0, 0.0);
        double rr = bv.x * bv.x + bv.y * bv.y;
        for (int off = 32; off > 0; off >>= 1) rr += __shfl_down(rr, off);
        if ((threadIdx.x & 63) == 0) atomicAdd(&scal[0], rr);
    }
}

// ---------------------------------------------------------------------------
// k_cg_iter: one full CG iteration, 256 blocks x 256 threads.
//   t==0 recomputes alpha_{it-1}, beta_it from dot history (scal).
//   Replicated update: z = ws * p_it into LDS.
//   MV (coalesced): lane = j2, loop j1; rows k2 = k2b..k2b+3 per wave-quad;
//   per j1: 4 lane-contiguous vR loads + 1 conflict-free LDS z load.
//   Wave-reduce over j2; lane 0 writes Ap/r/p/x (parity-out) + dot partials.
//   scal: [0] = rz0; [1+3k..3+3k] = (pAp, rAp, ApAp) of iter k.
//   rz recurrence: rz+ = rz - 2a<r,Ap> + a^2|Ap|^2 (algebraically == ref).
// ---------------------------------------------------------------------------
__global__ __launch_bounds__(256) void k_cg_iter(
        const double2* __restrict__ vR, const float* __restrict__ wsv,
        const float* __restrict__ sig2,
        const double2* __restrict__ pin, double2* __restrict__ pout,
        const double2* __restrict__ rin, double2* __restrict__ rout,
        const double2* __restrict__ xin, double2* __restrict__ xout,
        const double2* __restrict__ apin, double2* __restrict__ apout,
        double* __restrict__ scal, int it)
{
    __shared__ double2 zs[4096];
    __shared__ double s_ab[2];
    __shared__ double redd[4][3];
    int b = blockIdx.x, t = threadIdx.x;

    if (t == 0) {
        double alpha = 0.0, beta = 0.0;
        if (it > 0) {
            double rz = scal[0], rzp = rz, alp = 0.0;
            for (int k = 0; k < it; ++k) {
                double pap = scal[1 + 3 * k], rap = scal[2 + 3 * k], apap = scal[3 + 3 * k];
                double al = rz / (pap + 1e-30);
                rzp = rz; alp = al;
                rz = fma(al, fma(al, apap, -2.0 * rap), rz);
            }
            alpha = alp; beta = rz / (rzp + 1e-30);
        }
        s_ab[0] = alpha; s_ab[1] = beta;
    }
    __syncthreads();
    double alpha = s_ab[0], beta = s_ab[1];

    // replicated update: z = ws * p_new
    for (int s = 0; s < 16; ++s) {
        int i = t + 256 * s;
        double2 rv = rin[i];
        if (it > 0) {
            double2 ap = apin[i];
            rv.x -= alpha * ap.x; rv.y -= alpha * ap.y;
        }
        double2 pvv = pin[i];
        double2 pn = make_double2(rv.x + beta * pvv.x, rv.y + beta * pvv.y);
        double w = (double)wsv[i];
        zs[i] = make_double2(w * pn.x, w * pn.y);
    }
    __syncthreads();

    // coalesced direct Toeplitz MV: lane = j2, loop j1
    int rq = t >> 6, j2 = t & 63;
    int k1 = b >> 2;
    int k2b = (b & 3) * 16 + rq * 4;
    double2 acc[4];
    #pragma unroll
    for (int i = 0; i < 4; ++i) acc[i] = make_double2(0.0, 0.0);
    const double2* vbase = vR + (k1 + 64) * 128 + (k2b - j2 + 64);
    const double2* zp = zs + j2;
    #pragma unroll 4
    for (int j1 = 0; j1 < 64; ++j1) {
        double2 zj = zp[j1 * 64];
        const double2* vr = vbase - j1 * 128;
        #pragma unroll
        for (int i = 0; i < 4; ++i) dmac(acc[i], vr[i], zj);
    }

    #pragma unroll
    for (int off = 32; off > 0; off >>= 1)
        #pragma unroll
        for (int i = 0; i < 4; ++i) {
            acc[i].x += __shfl_down(acc[i].x, off);
            acc[i].y += __shfl_down(acc[i].y, off);
        }

    if (j2 == 0) {
        double s2 = (double)sig2[0];
        double d1 = 0.0, d2 = 0.0, d3 = 0.0;
        #pragma unroll
        for (int i = 0; i < 4; ++i) {
            int k = b * 16 + rq * 4 + i;
            double2 rv = rin[k];
            if (it > 0) {
                double2 ap = apin[k];
                rv.x -= alpha * ap.x; rv.y -= alpha * ap.y;
            }
            double2 pvv = pin[k];
            double2 pn = make_double2(rv.x + beta * pvv.x, rv.y + beta * pvv.y);
            double w = (double)wsv[k];
            double2 apn = make_double2(w * acc[i].x + s2 * pn.x,
                                       w * acc[i].y + s2 * pn.y);
            apout[k] = apn; rout[k] = rv; pout[k] = pn;
            double2 xv = xin[k];
            xout[k] = make_double2(xv.x + alpha * pvv.x, xv.y + alpha * pvv.y);
            d1 += pn.x * apn.x + pn.y * apn.y;
            d2 += rv.x * apn.x + rv.y * apn.y;
            d3 += apn.x * apn.x + apn.y * apn.y;
        }
        redd[rq][0] = d1; redd[rq][1] = d2; redd[rq][2] = d3;
    }
    __syncthreads();
    if (t == 0) {
        double a = 0.0, bb = 0.0, c = 0.0;
        for (int q = 0; q < 4; ++q) { a += redd[q][0]; bb += redd[q][1]; c += redd[q][2]; }
        atomicAdd(&scal[1 + 3 * it], a);
        atomicAdd(&scal[2 + 3 * it], bb);
        atomicAdd(&scal[3 + 3 * it], c);
    }
}

// ---------------------------------------------------------------------------
// k_eval: mu[b] = Re( sum_j e1[j] * sum_k alpha[j,k] e2[k] ),
// alpha = ws * (x_49 + alpha_49 * p_49)  (final CG update folded in).
// ---------------------------------------------------------------------------
__global__ __launch_bounds__(64) void k_eval(const float* __restrict__ xnew,
                                             const float* __restrict__ wsv,
                                             const double2* __restrict__ xsol,
                                             const double2* __restrict__ psol,
                                             const double* __restrict__ scal,
                                             float* __restrict__ out, int B)
{
    __shared__ float2 al[4096];
    __shared__ double s_al;
    int t = threadIdx.x;
    int b = blockIdx.x * 64 + t;
    if (t == 0) {
        double rz = scal[0], alp = 0.0;
        for (int k = 0; k < 50; ++k) {
            double pap = scal[1 + 3 * k], rap = scal[2 + 3 * k], apap = scal[3 + 3 * k];
            double a2 = rz / (pap + 1e-30);
            alp = a2;
            rz = fma(a2, fma(a2, apap, -2.0 * rap), rz);
        }
        s_al = alp;
    }
    __syncthreads();
    double alpha49 = s_al;
    for (int i = t; i < 4096; i += 64) {
        double2 xv = xsol[i];
        double2 pv = psol[i];
        double w = (double)wsv[i];
        al[i] = make_float2((float)(w * (xv.x + alpha49 * pv.x)),
                            (float)(w * (xv.y + alpha49 * pv.y)));
    }
    float x0 = 0.f, x1 = 0.f;
    if (b < B) { x0 = xnew[2 * b]; x1 = xnew[2 * b + 1]; }
    __syncthreads();
    double2 wstep; { double sn, cs; sincospi((double)x1, &sn, &cs); wstep = make_double2(cs, sn); }
    double mu = 0.0;
    for (int jg = 0; jg < 4; ++jg) {
        float2 tacc[16];
        for (int q = 0; q < 16; ++q) tacc[q] = make_float2(0.f, 0.f);
        double2 e2; { double sn, cs; sincospi(-32.0 * (double)x1, &sn, &cs); e2 = make_double2(cs, sn); }
        for (int k = 0; k < 64; ++k) {
            float2 e2f = make_float2((float)e2.x, (float)e2.y);
            for (int q = 0; q < 16; ++q) {
                int j = jg * 16 + q;
                float2 a = al[j * 64 + k];
                tacc[q].x += a.x * e2f.x - a.y * e2f.y;
                tacc[q].y += a.x * e2f.y + a.y * e2f.x;
            }
            e2 = make_double2(e2.x * wstep.x - e2.y * wstep.y,
                              e2.x * wstep.y + e2.y * wstep.x);
        }
        for (int q = 0; q < 16; ++q) {
            int j = jg * 16 + q;
            double sn, cs;
            sincospi((double)x0 * (double)(j - 32), &sn, &cs);
            mu += cs * (double)tacc[q].x - sn * (double)tacc[q].y;
        }
    }
    if (b < B) out[b] = (float)mu;
}

// ---------------------------------------------------------------------------

extern "C" void kernel_launch(void* const* d_in, const int* in_sizes, int n_in,
                              void* d_out, int out_size, void* d_ws, size_t ws_size,
                              hipStream_t stream)
{
    const float* x    = (const float*)d_in[0];
    const float* y    = (const float*)d_in[1];
    const float* xnew = (const float*)d_in[2];
    const float* wsv  = (const float*)d_in[3];
    const float* sig2 = (const float*)d_in[4];
    int N = in_sizes[1];
    int B = in_sizes[2] / 2;

    char* base = (char*)d_ws;
    size_t o = 0;
    double2* vR  = (double2*)(base + o); o += 262144;    // 128x128 Toeplitz table
    double* scal = (double*)(base + o);  o += 4096;      // [0]=rz0, then 50 triples
    double2* rb[2], *pb[2], *xb[2], *ab[2];
    for (int q = 0; q < 2; ++q) { rb[q] = (double2*)(base + o); o += 65536; }
    for (int q = 0; q < 2; ++q) { pb[q] = (double2*)(base + o); o += 65536; }
    for (int q = 0; q < 2; ++q) { xb[q] = (double2*)(base + o); o += 65536; }
    for (int q = 0; q < 2; ++q) { ab[q] = (double2*)(base + o); o += 65536; }
    size_t avail = (ws_size > o) ? ws_size - o : 0;
    int cv = (int)(avail / 139264);                      // 128KB v + 8KB fy per unit
    if (cv > 384) cv = 384;
    if (cv < 16) cv = 16;
    cv &= ~15;                                           // cv%8==0, cf%4==0
    int cf = cv / 4;
    float* pv = (float*)(base + o); o += (size_t)cv * 131072;
    float* pf = (float*)(base + o);

    hipMemsetAsync(vR, 0, 262144 + 4096, stream);        // vR + scal contiguous

    k_outer<<<cv + cf, 256, 0, stream>>>(x, y, pv, pf, N, cv, cf);
    k_reduce<<<528, 256, 0, stream>>>(pv, pf, wsv, (double*)vR,
                                      rb[0], pb[0], xb[0], scal, cv, cf);

    for (int it = 0; it < 50; ++it) {
        int in = it & 1, op = in ^ 1;
        k_cg_iter<<<256, 256, 0, stream>>>(vR, wsv, sig2,
                                           pb[in], pb[op], rb[in], rb[op],
                                           xb[in], xb[op], ab[in], ab[op],
                                           scal, it);
    }
    // after it=49: final state (x_49, p_49) in parity-0 buffers
    k_eval<<<(B + 63) / 64, 64, 0, stream>>>(xnew, wsv, xb[0], pb[0], scal,
                                             (float*)d_out, B);
}